// Round 19
// baseline (339.104 us; speedup 1.0000x reference)
//
#include <hip/hip_runtime.h>
#include <hip/hip_bf16.h>
#include <math.h>

#define NP 100000
#define NA 50000
#define DIM 128
#define NH 4
#define DKK 32
#define EC 600000
#define EW 300000
#define ER 300000
#define CAP 32          // bucket capacity per dst (Poisson(6) tail ~1e-9)
#define SCL 0.17677669529663687f   // 1/sqrt(32)

#define CDIV(a,b) (((a)+(b)-1)/(b))

typedef __attribute__((ext_vector_type(8))) short bf16x8;
typedef __attribute__((ext_vector_type(4))) float f32x4;
typedef __attribute__((ext_vector_type(2))) float f32x2;

__device__ __forceinline__ ushort f2b(float f){
  unsigned u = __float_as_uint(f);
  unsigned r = u + 0x7FFFu + ((u>>16)&1u);   // RNE
  return (ushort)(r>>16);
}
__device__ __forceinline__ float blo(unsigned u){ return __uint_as_float(u<<16); }
__device__ __forceinline__ float bhi(unsigned u){ return __uint_as_float(u & 0xFFFF0000u); }

// ---------------- small weight casts (Wq, Wa) ----------------
struct C2Args { const float4* in[2]; uint2* out[2]; };
__global__ void k_cast2(C2Args a){
  int s = blockIdx.y;
  int i = blockIdx.x*256 + threadIdx.x;   // 8192 float4 per slice
  float4 v = a.in[s][i];
  uint2 o;
  o.x = (unsigned)f2b(v.x) | ((unsigned)f2b(v.y)<<16);
  o.y = (unsigned)f2b(v.z) | ((unsigned)f2b(v.w)<<16);
  a.out[s][i] = o;
}

__global__ void k_zero_i(int* p, int n){
  int i = blockIdx.x*blockDim.x + threadIdx.x;
  if (i < n) p[i] = 0;
}

// ---------------- fuse rel matrices into bf16 projection weights (all 3 rels) ----------------
__global__ void k_fuse(const float* __restrict__ Wk, const float* __restrict__ bk,
                       const float* __restrict__ Wv, const float* __restrict__ bv,
                       const float* __restrict__ rel_att, const float* __restrict__ rel_msg,
                       ushort* __restrict__ Wfb_all, float* __restrict__ bfu_all){
  int rel = blockIdx.x >> 7;
  int ts = (rel==1) ? 1 : 0;
  ushort* Wfb = Wfb_all + rel*32768;
  float*  bfu = bfu_all + rel*256;
  int idx = (blockIdx.x & 127)*256 + threadIdx.x;   // 0..32767
  int which = idx >> 14;
  int rem = idx & 16383;
  int op = rem >> 7;
  int j  = rem & 127;
  int h = op >> 5, jp = op & 31;
  const float* W  = which ? Wv : Wk;
  const float* R  = which ? rel_msg : rel_att;
  const float* Wt = W + (size_t)ts*DIM*DIM;
  const float* Re = R + (((size_t)rel*NH + h)*DKK)*DKK + jp;
  float acc = 0.f;
  #pragma unroll
  for (int i=0;i<DKK;i++) acc += Wt[(h*DKK+i)*DIM + j] * Re[(size_t)i*DKK];
  Wfb[which*16384 + op*DIM + j] = f2b(acc);
  if (idx < 256){
    int w2 = idx >> 7; int op2 = idx & 127; int h2 = op2>>5, jp2 = op2&31;
    const float* bsrc = (w2 ? bv : bk) + (size_t)ts*DIM;
    const float* R2 = (w2 ? rel_msg : rel_att) + (((size_t)rel*NH + h2)*DKK)*DKK + jp2;
    float accb = 0.f;
    #pragma unroll
    for (int i=0;i<DKK;i++) accb += bsrc[h2*DKK+i]*R2[(size_t)i*DKK];
    bfu[w2*DIM + op2] = accb;
  }
}

// ---------------- mega GEMM v2 + per-panel output stride (KV interleave) ----------------
struct MArgs {
  const float* X[3];
  const ushort* W[3][3];
  const float* b[3][3];
  ushort* Y[3][3];
  int ystride[3][3];     // row stride in ushorts
  int N[3];
  int npan[3];
  int base[3];
};
__global__ __launch_bounds__(512) void k_mega(MArgs g){
  int b = blockIdx.x;
  int seg = (b >= g.base[2]) ? 2 : ((b >= g.base[1]) ? 1 : 0);
  int local = b - g.base[seg];
  int N = g.N[seg];
  int tile = local*64;
  if (tile >= N) return;
  int tid = threadIdx.x;
  int wv = tid >> 6, l = tid & 63;
  int lr = l & 15, lk = l >> 4;
  int rowg = wv >> 1, colg = wv & 1;
  int arow = tile + rowg*16 + lr;
  int ar = (arow < N) ? arow : 0;
  const float4* Ar = (const float4*)(g.X[seg] + (size_t)ar*DIM);
  bf16x8 A[4];
  #pragma unroll
  for (int kc=0;kc<4;kc++){
    float4 u = Ar[kc*8 + lk*2];
    float4 v = Ar[kc*8 + lk*2 + 1];
    bf16x8 a;
    a[0]=(short)f2b(u.x); a[1]=(short)f2b(u.y); a[2]=(short)f2b(u.z); a[3]=(short)f2b(u.w);
    a[4]=(short)f2b(v.x); a[5]=(short)f2b(v.y); a[6]=(short)f2b(v.z); a[7]=(short)f2b(v.w);
    A[kc] = a;
  }
  __shared__ __align__(16) ushort Wl[128*136];    // 34.8 KB weight panel (uint4 stride 17)
  __shared__ __align__(16) ushort Ost[64*136];    // 17.4 KB output staging
  uint4* Wl4 = (uint4*)Wl;
  int npan = g.npan[seg];
  for (int p=0; p<npan; ++p){
    const uint4* Ws = (const uint4*)g.W[seg][p];
    #pragma unroll
    for (int i=0;i<4;i++){
      int idx = i*512 + tid;                 // 2048 uint4 = 32KB panel
      uint4 v = Ws[idx];
      int r = idx >> 4, c = idx & 15;
      Wl4[r*17 + c] = v;
    }
    __syncthreads();
    const float* bias = g.b[seg][p];
    #pragma unroll
    for (int ct=0; ct<4; ct++){
      int col = colg*64 + ct*16 + lr;
      f32x4 acc = {0.f,0.f,0.f,0.f};
      #pragma unroll
      for (int kc=0;kc<4;kc++){
        bf16x8 B = *(const bf16x8*)&Wl[col*136 + kc*32 + lk*8];
        acc = __builtin_amdgcn_mfma_f32_16x16x32_bf16(A[kc], B, acc, 0, 0, 0);
      }
      float bv = bias[col];
      #pragma unroll
      for (int j=0;j<4;j++)
        Ost[(rowg*16 + lk*4 + j)*136 + col] = f2b(acc[j] + bv);
    }
    __syncthreads();
    int orow = tid >> 3;                 // 0..63
    int oseg = (tid & 7)*2;
    int grow = tile + orow;
    if (grow < N){
      uint4* dst = (uint4*)(g.Y[seg][p] + (size_t)grow*g.ystride[seg][p]);
      const uint4* s = (const uint4*)Ost;
      dst[oseg]   = s[orow*17 + oseg];
      dst[oseg+1] = s[orow*17 + oseg + 1];
    }
    __syncthreads();
  }
}

// ---------------- 1-pass XCD-affine bucket scatter ----------------
struct BArgs { const int* dst[3]; const int* src[3]; int* cnt[3]; int* slots[3]; int E[3]; int n[3]; };
__global__ void k_bucket(BArgs a){
  int r = blockIdx.y;
  int E = a.E[r], n = a.n[r];
  const int* dst = a.dst[r];
  const int* srcv = a.src[r];
  int* cnt = a.cnt[r];
  int* slots = a.slots[r];
  int g = blockIdx.x & 7;
  int sub = blockIdx.x >> 3;            // 0..255
  int chunk = (n + 7) >> 3;
  int lo = g*chunk;
  int hi = lo + chunk; if (hi > n) hi = n;
  int per = (E + 255) >> 8;
  per = (per + 3) & ~3;                  // keep int4 alignment
  int e0 = sub*per;
  int e1 = e0 + per; if (e1 > E) e1 = E;
  for (int i = e0 + threadIdx.x*4; i < e1; i += 256*4){
    if (i + 4 <= e1){
      int4 d = *(const int4*)(dst + i);
      int4 s = *(const int4*)(srcv + i);
      if (d.x>=lo && d.x<hi){ int p=atomicAdd(&cnt[d.x],1); if(p<CAP) slots[(size_t)d.x*CAP+p]=s.x; }
      if (d.y>=lo && d.y<hi){ int p=atomicAdd(&cnt[d.y],1); if(p<CAP) slots[(size_t)d.y*CAP+p]=s.y; }
      if (d.z>=lo && d.z<hi){ int p=atomicAdd(&cnt[d.z],1); if(p<CAP) slots[(size_t)d.z*CAP+p]=s.z; }
      if (d.w>=lo && d.w<hi){ int p=atomicAdd(&cnt[d.w],1); if(p<CAP) slots[(size_t)d.w*CAP+p]=s.w; }
    } else {
      for (int j=i; j<e1; ++j){
        int d = dst[j];
        if (d>=lo && d<hi){ int p=atomicAdd(&cnt[d],1); if(p<CAP) slots[(size_t)d*CAP+p]=srcv[j]; }
      }
    }
  }
}

// ---------------- one 4-edge step: K and V halves of one 512B KV row per src ----------------
__device__ __forceinline__ void agg_step4(const unsigned* __restrict__ KV,
    const int4* __restrict__ sl4,
    int i, int deg, int nsrc, float qx, float qy, int lane,
    f32x2& av, float& z)
{
  int4 s4 = sl4[i>>2];
  int s0 = ((unsigned)s4.x < (unsigned)nsrc) ? s4.x : 0;
  int s1 = ((unsigned)s4.y < (unsigned)nsrc) ? s4.y : 0;
  int s2 = ((unsigned)s4.z < (unsigned)nsrc) ? s4.z : 0;
  int s3 = ((unsigned)s4.w < (unsigned)nsrc) ? s4.w : 0;
  bool v1 = (i+1 < deg), v2 = (i+2 < deg), v3 = (i+3 < deg);
  const unsigned* r0 = KV + (size_t)s0*128;
  const unsigned* r1 = KV + (size_t)s1*128;
  const unsigned* r2 = KV + (size_t)s2*128;
  const unsigned* r3 = KV + (size_t)s3*128;
  unsigned ku0 = r0[lane];
  unsigned ku1 = r1[lane];
  unsigned ku2 = r2[lane];
  unsigned ku3 = r3[lane];
  unsigned vu0 = r0[64 + lane];
  unsigned vu1 = r1[64 + lane];
  unsigned vu2 = r2[64 + lane];
  unsigned vu3 = r3[64 + lane];
  float p0 = qx*blo(ku0) + qy*bhi(ku0);
  float p1 = qx*blo(ku1) + qy*bhi(ku1);
  float p2 = qx*blo(ku2) + qy*bhi(ku2);
  float p3 = qx*blo(ku3) + qy*bhi(ku3);
  #pragma unroll
  for (int d=1; d<16; d<<=1){
    p0 += __shfl_xor(p0, d);
    p1 += __shfl_xor(p1, d);
    p2 += __shfl_xor(p2, d);
    p3 += __shfl_xor(p3, d);
  }
  float e0 = __expf(p0);
  float e1 = v1 ? __expf(p1) : 0.f;
  float e2 = v2 ? __expf(p2) : 0.f;
  float e3 = v3 ? __expf(p3) : 0.f;
  z += (e0+e1)+(e2+e3);
  f32x2 w0 = {blo(vu0), bhi(vu0)};
  f32x2 w1 = {blo(vu1), bhi(vu1)};
  f32x2 w2 = {blo(vu2), bhi(vu2)};
  f32x2 w3 = {blo(vu3), bhi(vu3)};
  av += (w0*e0 + w1*e1) + (w2*e2 + w3*e3);
}

// ---------------- fused attention + final GEMM + skip (one block = 32 output rows) ----------------
struct AFArgs {
  const unsigned *QP, *QA, *KV0, *KV1, *KV2;
  const int *slots, *cnt;
  const float *pri;
  const ushort *WaP, *WaA;
  const float *baP, *baA;
  const float *hP, *hA;
  float *outP, *outA;
  const float *skip;
  int PB;                     // paper block count
};
__global__ __launch_bounds__(256) void k_attnfin(AFArgs a){
  bool isP = (blockIdx.x < (unsigned)a.PB);
  int wbase = isP ? blockIdx.x*32 : (blockIdx.x - a.PB)*32;
  int N = isP ? NP : NA;
  int tid = threadIdx.x;
  int wid = tid >> 6;
  int lane = tid & 63;
  int h = lane >> 4;
  __shared__ float Ls[32][132];
  __shared__ int nextrow;
  if (tid == 0) nextrow = 0;
  __syncthreads();
  // ---- phase 1: attention, dynamic row queue (load-balanced across 4 waves) ----
  for (;;){
    int row;
    if (lane == 0) row = atomicAdd(&nextrow, 1);
    row = __shfl(row, 0);
    if (row >= 32) break;
    int w = wbase + row;
    if (w < N){
      f32x2 o;
      if (isP){
        unsigned qu = a.QP[(size_t)w*64 + lane];
        float qx = blo(qu), qy = bhi(qu);
        float s0f = a.pri[h]*SCL, s1f = a.pri[NH+h]*SCL;
        float qx0 = qx*s0f, qy0 = qy*s0f;
        float qx1 = qx*s1f, qy1 = qy*s1f;
        int d0 = a.cnt[w];      if (d0 > CAP) d0 = CAP;
        int d1 = a.cnt[NP + w]; if (d1 > CAP) d1 = CAP;
        const int4* sl0 = (const int4*)(a.slots + (size_t)w*CAP);
        const int4* sl1 = (const int4*)(a.slots + ((size_t)NP+w)*CAP);
        f32x2 x = {0.f,0.f}, y = {0.f,0.f};
        float zx = 0.f, zy = 0.f;
        int nmax = (d0 > d1) ? d0 : d1;
        for (int i = 0; i < nmax; i += 4){
          if (i < d0) agg_step4(a.KV0, sl0, i, d0, NP, qx0, qy0, lane, x, zx);
          if (i < d1) agg_step4(a.KV1, sl1, i, d1, NA, qx1, qy1, lane, y, zy);
        }
        float ix = (zx > 0.f) ? 1.f/zx : 0.f;
        float iy = (zy > 0.f) ? 1.f/zy : 0.f;
        o = x*ix + y*iy;
      } else {
        unsigned qu = a.QA[(size_t)w*64 + lane];
        float qx = blo(qu), qy = bhi(qu);
        float s2f = a.pri[2*NH+h]*SCL;
        float qx2 = qx*s2f, qy2 = qy*s2f;
        int d2 = a.cnt[2*NP + w]; if (d2 > CAP) d2 = CAP;
        const int4* sl2 = (const int4*)(a.slots + ((size_t)2*NP+w)*CAP);
        f32x2 r = {0.f,0.f};
        float zr = 0.f;
        for (int i = 0; i < d2; i += 4)
          agg_step4(a.KV2, sl2, i, d2, NP, qx2, qy2, lane, r, zr);
        float ir = (zr > 0.f) ? 1.f/zr : 0.f;
        o = r*ir;
      }
      *(f32x2*)&Ls[row][2*lane] = o;
    }
  }
  __syncthreads();
  // ---- phase 2: 32x128 GEMM vs Wa + skip blend, A-fragments from LDS ----
  const ushort* Wb  = isP ? a.WaP : a.WaA;
  const float* bias = isP ? a.baP : a.baA;
  const float* hin  = isP ? a.hP  : a.hA;
  float* out        = isP ? a.outP : a.outA;
  float scale       = isP ? 0.5f : 1.0f;
  float alpha = 1.f/(1.f + expf(-a.skip[isP ? 0 : 1]));
  float beta  = 1.f - alpha;
  int lr = lane & 15, lk = lane >> 4;
  int r0loc = (wid&1)*16;
  int c0 = (wid>>1)*64;
  bf16x8 A[4];
  #pragma unroll
  for (int kc=0;kc<4;kc++){
    const float* src = &Ls[r0loc + lr][kc*32 + lk*8];
    bf16x8 aa;
    #pragma unroll
    for (int j=0;j<8;j++) aa[j] = (short)f2b(src[j]);
    A[kc] = aa;
  }
  __syncthreads();   // all A-frags read before Ls overwrite
  #pragma unroll
  for (int ct=0; ct<4; ct++){
    int col = c0 + ct*16 + lr;
    const bf16x8* Wrow = (const bf16x8*)(Wb + (size_t)col*DIM);
    f32x4 acc = {0.f,0.f,0.f,0.f};
    #pragma unroll
    for (int kc=0;kc<4;kc++)
      acc = __builtin_amdgcn_mfma_f32_16x16x32_bf16(A[kc], Wrow[kc*4+lk], acc, 0, 0, 0);
    float bv = bias[col];
    #pragma unroll
    for (int j=0;j<4;j++){
      int lrow = r0loc + lk*4 + j;
      Ls[lrow][col] = scale*acc[j] + bv;
    }
  }
  __syncthreads();
  int orow = tid >> 3;                    // 0..31
  int ocb  = (tid & 7)*16;                // float col base
  int row  = wbase + orow;
  if (row < N){
    const float4* H4 = (const float4*)hin;
    float4* O4 = (float4*)out;
    #pragma unroll
    for (int q=0;q<4;q++){
      float4 tv = *(const float4*)&Ls[orow][ocb + q*4];
      float4 hv = H4[(size_t)row*32 + (ocb>>2) + q];
      float4 o;
      o.x = alpha*tv.x + beta*hv.x;
      o.y = alpha*tv.y + beta*hv.y;
      o.z = alpha*tv.z + beta*hv.z;
      o.w = alpha*tv.w + beta*hv.w;
      O4[(size_t)row*32 + (ocb>>2) + q] = o;
    }
  }
}

extern "C" void kernel_launch(void* const* d_in, const int* in_sizes, int n_in,
                              void* d_out, int out_size, void* d_ws, size_t ws_size,
                              hipStream_t stream) {
  const float* h_paper = (const float*)d_in[0];
  const float* h_author= (const float*)d_in[1];
  const float* Wk = (const float*)d_in[2];
  const float* bk = (const float*)d_in[3];
  const float* Wq = (const float*)d_in[4];
  const float* bq = (const float*)d_in[5];
  const float* Wv = (const float*)d_in[6];
  const float* bv = (const float*)d_in[7];
  const float* Wa = (const float*)d_in[8];
  const float* ba = (const float*)d_in[9];
  const float* rel_att = (const float*)d_in[10];
  const float* rel_msg = (const float*)d_in[11];
  const float* rel_pri = (const float*)d_in[12];
  const float* skip    = (const float*)d_in[13];
  const int* cites_src = (const int*)d_in[14];
  const int* cites_dst = (const int*)d_in[15];
  const int* writes_src= (const int*)d_in[16];
  const int* writes_dst= (const int*)d_in[17];
  const int* rev_src   = (const int*)d_in[18];
  const int* rev_dst   = (const int*)d_in[19];

  // ---- workspace layout (16B aligned) ----
  ushort* qbP = (ushort*)d_ws;                         // NP*128
  ushort* qbA = qbP + (size_t)NP*DIM;                  // NA*128
  ushort* KV0 = qbA + (size_t)NA*DIM;                  // NP*256 (K|V interleaved rows)
  ushort* KV1 = KV0 + (size_t)NP*256;                  // NA*256
  ushort* KV2 = KV1 + (size_t)NA*256;                  // NP*256
  ushort* Wqb = KV2 + (size_t)NP*256;                  // 32768
  ushort* Wab = Wqb + 32768;                           // 32768
  ushort* Wfb = Wab + 32768;                           // 3*32768
  float*  bfu = (float*)(Wfb + 3*32768);               // 3*256
  int* ib = (int*)(bfu + 3*256);
  const int NDST_TOT = 2*NP + NA;                      // 250000
  int* cnt_all   = ib;           ib += NDST_TOT;
  int* slots_all = ib;                                  // 250000*CAP ints = 32 MB

  float* t_paper  = (float*)d_out;
  float* t_author = (float*)d_out + (size_t)NP*DIM;

  const int cntB[3] = {0, NP, 2*NP};

  // 1) weight casts (Wq, Wa)
  {
    C2Args a;
    a.in[0]=(const float4*)Wq; a.out[0]=(uint2*)Wqb;
    a.in[1]=(const float4*)Wa; a.out[1]=(uint2*)Wab;
    k_cast2<<<dim3(32,2),256,0,stream>>>(a);
  }
  // 2) fuse all 3 relations
  k_fuse<<<384,256,0,stream>>>(Wk, bk, Wv, bv, rel_att, rel_msg, Wfb, bfu);
  // 3) bucket CSR (1 pass, XCD-affine)
  k_zero_i<<<CDIV(NDST_TOT,256),256,0,stream>>>(cnt_all, NDST_TOT);
  {
    BArgs b;
    const int* dsts[3] = {cites_dst, writes_dst, rev_dst};
    const int* srcs[3] = {cites_src, writes_src, rev_src};
    int Es[3] = {EC, EW, ER};
    int ns[3] = {NP, NP, NA};
    for (int r=0;r<3;r++){
      b.dst[r]=dsts[r]; b.src[r]=srcs[r];
      b.cnt[r]=cnt_all+cntB[r];
      b.slots[r]=slots_all+(size_t)cntB[r]*CAP;
      b.E[r]=Es[r]; b.n[r]=ns[r];
    }
    k_bucket<<<dim3(2048,3),256,0,stream>>>(b);
  }
  // 4) mega GEMM v2: seg0 papers{q,K0,V0}, seg1 authors{q,K1,V1}, seg2 papers{K2,V2}
  {
    const int T0 = CDIV(NP,64), T1 = CDIV(NA,64), T2 = CDIV(NP,64);
    MArgs m;
    m.base[0]=0; m.base[1]=T0; m.base[2]=T0+T1;
    m.X[0]=h_paper;  m.N[0]=NP; m.npan[0]=3;
    m.W[0][0]=Wqb;        m.b[0][0]=bq;        m.Y[0][0]=qbP;      m.ystride[0][0]=128;
    m.W[0][1]=Wfb;        m.b[0][1]=bfu;       m.Y[0][1]=KV0;      m.ystride[0][1]=256;
    m.W[0][2]=Wfb+16384;  m.b[0][2]=bfu+DIM;   m.Y[0][2]=KV0+128;  m.ystride[0][2]=256;
    m.X[1]=h_author; m.N[1]=NA; m.npan[1]=3;
    m.W[1][0]=Wqb+16384;        m.b[1][0]=bq+DIM;        m.Y[1][0]=qbA;      m.ystride[1][0]=128;
    m.W[1][1]=Wfb+32768;        m.b[1][1]=bfu+256;       m.Y[1][1]=KV1;      m.ystride[1][1]=256;
    m.W[1][2]=Wfb+32768+16384;  m.b[1][2]=bfu+256+DIM;   m.Y[1][2]=KV1+128;  m.ystride[1][2]=256;
    m.X[2]=h_paper;  m.N[2]=NP; m.npan[2]=2;
    m.W[2][0]=Wfb+2*32768;        m.b[2][0]=bfu+512;       m.Y[2][0]=KV2;      m.ystride[2][0]=256;
    m.W[2][1]=Wfb+2*32768+16384;  m.b[2][1]=bfu+512+DIM;   m.Y[2][1]=KV2+128;  m.ystride[2][1]=256;
    m.W[2][2]=Wfb;                m.b[2][2]=bfu;           m.Y[2][2]=KV2;      m.ystride[2][2]=256;  // unused
    k_mega<<<T0+T1+T2,512,0,stream>>>(m);
  }
  // 5) fused attention + final GEMM + skip (papers then authors, one launch)
  {
    const int PB = CDIV(NP,32);          // 3125 exactly
    const int AB = CDIV(NA,32);          // 1563
    AFArgs a;
    a.QP = (const unsigned*)qbP;  a.QA = (const unsigned*)qbA;
    a.KV0 = (const unsigned*)KV0; a.KV1 = (const unsigned*)KV1; a.KV2 = (const unsigned*)KV2;
    a.slots = slots_all; a.cnt = cnt_all;
    a.pri = rel_pri;
    a.WaP = Wab; a.WaA = Wab + 16384;
    a.baP = ba;  a.baA = ba + DIM;
    a.hP = h_paper; a.hA = h_author;
    a.outP = t_paper; a.outA = t_author;
    a.skip = skip;
    a.PB = PB;
    k_attnfin<<<PB+AB,256,0,stream>>>(a);
  }
}

// Round 20
// 326.958 us; speedup vs baseline: 1.0371x; 1.0371x over previous
//
#include <hip/hip_runtime.h>
#include <hip/hip_bf16.h>
#include <math.h>

#define NP 100000
#define NA 50000
#define DIM 128
#define NH 4
#define DKK 32
#define EC 600000
#define EW 300000
#define ER 300000
#define CAP 32          // bucket capacity per dst (Poisson(6) tail ~1e-9)
#define SCL 0.17677669529663687f   // 1/sqrt(32)

#define CDIV(a,b) (((a)+(b)-1)/(b))

typedef __attribute__((ext_vector_type(8))) short bf16x8;
typedef __attribute__((ext_vector_type(4))) float f32x4;
typedef __attribute__((ext_vector_type(2))) float f32x2;

__device__ __forceinline__ ushort f2b(float f){
  unsigned u = __float_as_uint(f);
  unsigned r = u + 0x7FFFu + ((u>>16)&1u);   // RNE
  return (ushort)(r>>16);
}
__device__ __forceinline__ float blo(unsigned u){ return __uint_as_float(u<<16); }
__device__ __forceinline__ float bhi(unsigned u){ return __uint_as_float(u & 0xFFFF0000u); }

// ---------------- small weight casts (Wq, Wa) ----------------
struct C2Args { const float4* in[2]; uint2* out[2]; };
__global__ void k_cast2(C2Args a){
  int s = blockIdx.y;
  int i = blockIdx.x*256 + threadIdx.x;   // 8192 float4 per slice
  float4 v = a.in[s][i];
  uint2 o;
  o.x = (unsigned)f2b(v.x) | ((unsigned)f2b(v.y)<<16);
  o.y = (unsigned)f2b(v.z) | ((unsigned)f2b(v.w)<<16);
  a.out[s][i] = o;
}

__global__ void k_zero_i(int* p, int n){
  int i = blockIdx.x*blockDim.x + threadIdx.x;
  if (i < n) p[i] = 0;
}

// ---------------- fuse rel matrices into bf16 projection weights (all 3 rels) ----------------
__global__ void k_fuse(const float* __restrict__ Wk, const float* __restrict__ bk,
                       const float* __restrict__ Wv, const float* __restrict__ bv,
                       const float* __restrict__ rel_att, const float* __restrict__ rel_msg,
                       ushort* __restrict__ Wfb_all, float* __restrict__ bfu_all){
  int rel = blockIdx.x >> 7;
  int ts = (rel==1) ? 1 : 0;
  ushort* Wfb = Wfb_all + rel*32768;
  float*  bfu = bfu_all + rel*256;
  int idx = (blockIdx.x & 127)*256 + threadIdx.x;   // 0..32767
  int which = idx >> 14;
  int rem = idx & 16383;
  int op = rem >> 7;
  int j  = rem & 127;
  int h = op >> 5, jp = op & 31;
  const float* W  = which ? Wv : Wk;
  const float* R  = which ? rel_msg : rel_att;
  const float* Wt = W + (size_t)ts*DIM*DIM;
  const float* Re = R + (((size_t)rel*NH + h)*DKK)*DKK + jp;
  float acc = 0.f;
  #pragma unroll
  for (int i=0;i<DKK;i++) acc += Wt[(h*DKK+i)*DIM + j] * Re[(size_t)i*DKK];
  Wfb[which*16384 + op*DIM + j] = f2b(acc);
  if (idx < 256){
    int w2 = idx >> 7; int op2 = idx & 127; int h2 = op2>>5, jp2 = op2&31;
    const float* bsrc = (w2 ? bv : bk) + (size_t)ts*DIM;
    const float* R2 = (w2 ? rel_msg : rel_att) + (((size_t)rel*NH + h2)*DKK)*DKK + jp2;
    float accb = 0.f;
    #pragma unroll
    for (int i=0;i<DKK;i++) accb += bsrc[h2*DKK+i]*R2[(size_t)i*DKK];
    bfu[w2*DIM + op2] = accb;
  }
}

// ---------------- mega GEMM v2 + per-panel output stride (KV interleave) ----------------
struct MArgs {
  const float* X[3];
  const ushort* W[3][3];
  const float* b[3][3];
  ushort* Y[3][3];
  int ystride[3][3];     // row stride in ushorts
  int N[3];
  int npan[3];
  int base[3];
};
__global__ __launch_bounds__(512) void k_mega(MArgs g){
  int b = blockIdx.x;
  int seg = (b >= g.base[2]) ? 2 : ((b >= g.base[1]) ? 1 : 0);
  int local = b - g.base[seg];
  int N = g.N[seg];
  int tile = local*64;
  if (tile >= N) return;
  int tid = threadIdx.x;
  int wv = tid >> 6, l = tid & 63;
  int lr = l & 15, lk = l >> 4;
  int rowg = wv >> 1, colg = wv & 1;
  int arow = tile + rowg*16 + lr;
  int ar = (arow < N) ? arow : 0;
  const float4* Ar = (const float4*)(g.X[seg] + (size_t)ar*DIM);
  bf16x8 A[4];
  #pragma unroll
  for (int kc=0;kc<4;kc++){
    float4 u = Ar[kc*8 + lk*2];
    float4 v = Ar[kc*8 + lk*2 + 1];
    bf16x8 a;
    a[0]=(short)f2b(u.x); a[1]=(short)f2b(u.y); a[2]=(short)f2b(u.z); a[3]=(short)f2b(u.w);
    a[4]=(short)f2b(v.x); a[5]=(short)f2b(v.y); a[6]=(short)f2b(v.z); a[7]=(short)f2b(v.w);
    A[kc] = a;
  }
  __shared__ __align__(16) ushort Wl[128*136];    // 34.8 KB weight panel (uint4 stride 17)
  __shared__ __align__(16) ushort Ost[64*136];    // 17.4 KB output staging
  uint4* Wl4 = (uint4*)Wl;
  int npan = g.npan[seg];
  for (int p=0; p<npan; ++p){
    const uint4* Ws = (const uint4*)g.W[seg][p];
    #pragma unroll
    for (int i=0;i<4;i++){
      int idx = i*512 + tid;                 // 2048 uint4 = 32KB panel
      uint4 v = Ws[idx];
      int r = idx >> 4, c = idx & 15;
      Wl4[r*17 + c] = v;
    }
    __syncthreads();
    const float* bias = g.b[seg][p];
    #pragma unroll
    for (int ct=0; ct<4; ct++){
      int col = colg*64 + ct*16 + lr;
      f32x4 acc = {0.f,0.f,0.f,0.f};
      #pragma unroll
      for (int kc=0;kc<4;kc++){
        bf16x8 B = *(const bf16x8*)&Wl[col*136 + kc*32 + lk*8];
        acc = __builtin_amdgcn_mfma_f32_16x16x32_bf16(A[kc], B, acc, 0, 0, 0);
      }
      float bv = bias[col];
      #pragma unroll
      for (int j=0;j<4;j++)
        Ost[(rowg*16 + lk*4 + j)*136 + col] = f2b(acc[j] + bv);
    }
    __syncthreads();
    int orow = tid >> 3;                 // 0..63
    int oseg = (tid & 7)*2;
    int grow = tile + orow;
    if (grow < N){
      uint4* dst = (uint4*)(g.Y[seg][p] + (size_t)grow*g.ystride[seg][p]);
      const uint4* s = (const uint4*)Ost;
      dst[oseg]   = s[orow*17 + oseg];
      dst[oseg+1] = s[orow*17 + oseg + 1];
    }
    __syncthreads();
  }
}

// ---------------- 1-pass XCD-affine bucket scatter ----------------
struct BArgs { const int* dst[3]; const int* src[3]; int* cnt[3]; int* slots[3]; int E[3]; int n[3]; };
__global__ void k_bucket(BArgs a){
  int r = blockIdx.y;
  int E = a.E[r], n = a.n[r];
  const int* dst = a.dst[r];
  const int* srcv = a.src[r];
  int* cnt = a.cnt[r];
  int* slots = a.slots[r];
  int g = blockIdx.x & 7;
  int sub = blockIdx.x >> 3;            // 0..255
  int chunk = (n + 7) >> 3;
  int lo = g*chunk;
  int hi = lo + chunk; if (hi > n) hi = n;
  int per = (E + 255) >> 8;
  per = (per + 3) & ~3;                  // keep int4 alignment
  int e0 = sub*per;
  int e1 = e0 + per; if (e1 > E) e1 = E;
  for (int i = e0 + threadIdx.x*4; i < e1; i += 256*4){
    if (i + 4 <= e1){
      int4 d = *(const int4*)(dst + i);
      int4 s = *(const int4*)(srcv + i);
      if (d.x>=lo && d.x<hi){ int p=atomicAdd(&cnt[d.x],1); if(p<CAP) slots[(size_t)d.x*CAP+p]=s.x; }
      if (d.y>=lo && d.y<hi){ int p=atomicAdd(&cnt[d.y],1); if(p<CAP) slots[(size_t)d.y*CAP+p]=s.y; }
      if (d.z>=lo && d.z<hi){ int p=atomicAdd(&cnt[d.z],1); if(p<CAP) slots[(size_t)d.z*CAP+p]=s.z; }
      if (d.w>=lo && d.w<hi){ int p=atomicAdd(&cnt[d.w],1); if(p<CAP) slots[(size_t)d.w*CAP+p]=s.w; }
    } else {
      for (int j=i; j<e1; ++j){
        int d = dst[j];
        if (d>=lo && d<hi){ int p=atomicAdd(&cnt[d],1); if(p<CAP) slots[(size_t)d*CAP+p]=srcv[j]; }
      }
    }
  }
}

// ---------------- one 4-edge step: K and V halves of one 512B KV row per src ----------------
__device__ __forceinline__ void agg_step4(const unsigned* __restrict__ KV,
    const int4* __restrict__ sl4,
    int i, int deg, int nsrc, float qx, float qy, int lane,
    f32x2& av, float& z)
{
  int4 s4 = sl4[i>>2];
  int s0 = ((unsigned)s4.x < (unsigned)nsrc) ? s4.x : 0;
  int s1 = ((unsigned)s4.y < (unsigned)nsrc) ? s4.y : 0;
  int s2 = ((unsigned)s4.z < (unsigned)nsrc) ? s4.z : 0;
  int s3 = ((unsigned)s4.w < (unsigned)nsrc) ? s4.w : 0;
  bool v1 = (i+1 < deg), v2 = (i+2 < deg), v3 = (i+3 < deg);
  const unsigned* r0 = KV + (size_t)s0*128;
  const unsigned* r1 = KV + (size_t)s1*128;
  const unsigned* r2 = KV + (size_t)s2*128;
  const unsigned* r3 = KV + (size_t)s3*128;
  unsigned ku0 = r0[lane];
  unsigned ku1 = r1[lane];
  unsigned ku2 = r2[lane];
  unsigned ku3 = r3[lane];
  unsigned vu0 = r0[64 + lane];
  unsigned vu1 = r1[64 + lane];
  unsigned vu2 = r2[64 + lane];
  unsigned vu3 = r3[64 + lane];
  float p0 = qx*blo(ku0) + qy*bhi(ku0);
  float p1 = qx*blo(ku1) + qy*bhi(ku1);
  float p2 = qx*blo(ku2) + qy*bhi(ku2);
  float p3 = qx*blo(ku3) + qy*bhi(ku3);
  #pragma unroll
  for (int d=1; d<16; d<<=1){
    p0 += __shfl_xor(p0, d);
    p1 += __shfl_xor(p1, d);
    p2 += __shfl_xor(p2, d);
    p3 += __shfl_xor(p3, d);
  }
  float e0 = __expf(p0);
  float e1 = v1 ? __expf(p1) : 0.f;
  float e2 = v2 ? __expf(p2) : 0.f;
  float e3 = v3 ? __expf(p3) : 0.f;
  z += (e0+e1)+(e2+e3);
  f32x2 w0 = {blo(vu0), bhi(vu0)};
  f32x2 w1 = {blo(vu1), bhi(vu1)};
  f32x2 w2 = {blo(vu2), bhi(vu2)};
  f32x2 w3 = {blo(vu3), bhi(vu3)};
  av += (w0*e0 + w1*e1) + (w2*e2 + w3*e3);
}

// ---------------- fused attention + final GEMM + skip (one block = 64 rows, 8 waves) ----------------
struct AFArgs {
  const unsigned *QP, *QA, *KV0, *KV1, *KV2;
  const int *slots, *cnt;
  const float *pri;
  const ushort *WaP, *WaA;
  const float *baP, *baA;
  const float *hP, *hA;
  float *outP, *outA;
  const float *skip;
  int PB;                     // paper block count
};
__global__ __launch_bounds__(512) void k_attnfin(AFArgs a){
  bool isP = (blockIdx.x < (unsigned)a.PB);
  int wbase = isP ? blockIdx.x*64 : (blockIdx.x - a.PB)*64;
  int N = isP ? NP : NA;
  int tid = threadIdx.x;
  int wid = tid >> 6;
  int lane = tid & 63;
  int h = lane >> 4;
  __shared__ float Ls[64][132];
  __shared__ int nextrow;
  if (tid == 0) nextrow = 0;
  __syncthreads();
  // ---- phase 1: attention, dynamic row queue over 64 rows x 8 waves ----
  for (;;){
    int row;
    if (lane == 0) row = atomicAdd(&nextrow, 1);
    row = __shfl(row, 0);
    if (row >= 64) break;
    int w = wbase + row;
    if (w < N){
      f32x2 o;
      if (isP){
        unsigned qu = a.QP[(size_t)w*64 + lane];
        float qx = blo(qu), qy = bhi(qu);
        float s0f = a.pri[h]*SCL, s1f = a.pri[NH+h]*SCL;
        float qx0 = qx*s0f, qy0 = qy*s0f;
        float qx1 = qx*s1f, qy1 = qy*s1f;
        int d0 = a.cnt[w];      if (d0 > CAP) d0 = CAP;
        int d1 = a.cnt[NP + w]; if (d1 > CAP) d1 = CAP;
        const int4* sl0 = (const int4*)(a.slots + (size_t)w*CAP);
        const int4* sl1 = (const int4*)(a.slots + ((size_t)NP+w)*CAP);
        f32x2 x = {0.f,0.f}, y = {0.f,0.f};
        float zx = 0.f, zy = 0.f;
        int nmax = (d0 > d1) ? d0 : d1;
        for (int i = 0; i < nmax; i += 4){
          if (i < d0) agg_step4(a.KV0, sl0, i, d0, NP, qx0, qy0, lane, x, zx);
          if (i < d1) agg_step4(a.KV1, sl1, i, d1, NA, qx1, qy1, lane, y, zy);
        }
        float ix = (zx > 0.f) ? 1.f/zx : 0.f;
        float iy = (zy > 0.f) ? 1.f/zy : 0.f;
        o = x*ix + y*iy;
      } else {
        unsigned qu = a.QA[(size_t)w*64 + lane];
        float qx = blo(qu), qy = bhi(qu);
        float s2f = a.pri[2*NH+h]*SCL;
        float qx2 = qx*s2f, qy2 = qy*s2f;
        int d2 = a.cnt[2*NP + w]; if (d2 > CAP) d2 = CAP;
        const int4* sl2 = (const int4*)(a.slots + ((size_t)2*NP+w)*CAP);
        f32x2 r = {0.f,0.f};
        float zr = 0.f;
        for (int i = 0; i < d2; i += 4)
          agg_step4(a.KV2, sl2, i, d2, NP, qx2, qy2, lane, r, zr);
        float ir = (zr > 0.f) ? 1.f/zr : 0.f;
        o = r*ir;
      }
      *(f32x2*)&Ls[row][2*lane] = o;
    }
  }
  __syncthreads();
  // ---- phase 2: 64x128 GEMM vs Wa + skip blend (8 waves: rowg=wid>>1, colg=wid&1) ----
  const ushort* Wb  = isP ? a.WaP : a.WaA;
  const float* bias = isP ? a.baP : a.baA;
  const float* hin  = isP ? a.hP  : a.hA;
  float* out        = isP ? a.outP : a.outA;
  float scale       = isP ? 0.5f : 1.0f;
  float alpha = 1.f/(1.f + expf(-a.skip[isP ? 0 : 1]));
  float beta  = 1.f - alpha;
  int lr = lane & 15, lk = lane >> 4;
  int rowg = wid >> 1, colg = wid & 1;
  int r0loc = rowg*16;
  int c0 = colg*64;
  bf16x8 A[4];
  #pragma unroll
  for (int kc=0;kc<4;kc++){
    const float* src = &Ls[r0loc + lr][kc*32 + lk*8];
    bf16x8 aa;
    #pragma unroll
    for (int j=0;j<8;j++) aa[j] = (short)f2b(src[j]);
    A[kc] = aa;
  }
  __syncthreads();   // all A-frags read before Ls overwrite
  #pragma unroll
  for (int ct=0; ct<4; ct++){
    int col = c0 + ct*16 + lr;
    const bf16x8* Wrow = (const bf16x8*)(Wb + (size_t)col*DIM);
    f32x4 acc = {0.f,0.f,0.f,0.f};
    #pragma unroll
    for (int kc=0;kc<4;kc++)
      acc = __builtin_amdgcn_mfma_f32_16x16x32_bf16(A[kc], Wrow[kc*4+lk], acc, 0, 0, 0);
    float bv = bias[col];
    #pragma unroll
    for (int j=0;j<4;j++){
      int lrow = r0loc + lk*4 + j;
      Ls[lrow][col] = scale*acc[j] + bv;
    }
  }
  __syncthreads();
  int orow = tid >> 3;                    // 0..63
  int ocb  = (tid & 7)*16;                // float col base
  int row  = wbase + orow;
  if (row < N){
    const float4* H4 = (const float4*)hin;
    float4* O4 = (float4*)out;
    #pragma unroll
    for (int q=0;q<4;q++){
      float4 tv = *(const float4*)&Ls[orow][ocb + q*4];
      float4 hv = H4[(size_t)row*32 + (ocb>>2) + q];
      float4 o;
      o.x = alpha*tv.x + beta*hv.x;
      o.y = alpha*tv.y + beta*hv.y;
      o.z = alpha*tv.z + beta*hv.z;
      o.w = alpha*tv.w + beta*hv.w;
      O4[(size_t)row*32 + (ocb>>2) + q] = o;
    }
  }
}

extern "C" void kernel_launch(void* const* d_in, const int* in_sizes, int n_in,
                              void* d_out, int out_size, void* d_ws, size_t ws_size,
                              hipStream_t stream) {
  const float* h_paper = (const float*)d_in[0];
  const float* h_author= (const float*)d_in[1];
  const float* Wk = (const float*)d_in[2];
  const float* bk = (const float*)d_in[3];
  const float* Wq = (const float*)d_in[4];
  const float* bq = (const float*)d_in[5];
  const float* Wv = (const float*)d_in[6];
  const float* bv = (const float*)d_in[7];
  const float* Wa = (const float*)d_in[8];
  const float* ba = (const float*)d_in[9];
  const float* rel_att = (const float*)d_in[10];
  const float* rel_msg = (const float*)d_in[11];
  const float* rel_pri = (const float*)d_in[12];
  const float* skip    = (const float*)d_in[13];
  const int* cites_src = (const int*)d_in[14];
  const int* cites_dst = (const int*)d_in[15];
  const int* writes_src= (const int*)d_in[16];
  const int* writes_dst= (const int*)d_in[17];
  const int* rev_src   = (const int*)d_in[18];
  const int* rev_dst   = (const int*)d_in[19];

  // ---- workspace layout (16B aligned) ----
  ushort* qbP = (ushort*)d_ws;                         // NP*128
  ushort* qbA = qbP + (size_t)NP*DIM;                  // NA*128
  ushort* KV0 = qbA + (size_t)NA*DIM;                  // NP*256 (K|V interleaved rows)
  ushort* KV1 = KV0 + (size_t)NP*256;                  // NA*256
  ushort* KV2 = KV1 + (size_t)NA*256;                  // NP*256
  ushort* Wqb = KV2 + (size_t)NP*256;                  // 32768
  ushort* Wab = Wqb + 32768;                           // 32768
  ushort* Wfb = Wab + 32768;                           // 3*32768
  float*  bfu = (float*)(Wfb + 3*32768);               // 3*256
  int* ib = (int*)(bfu + 3*256);
  const int NDST_TOT = 2*NP + NA;                      // 250000
  int* cnt_all   = ib;           ib += NDST_TOT;
  int* slots_all = ib;                                  // 250000*CAP ints = 32 MB

  float* t_paper  = (float*)d_out;
  float* t_author = (float*)d_out + (size_t)NP*DIM;

  const int cntB[3] = {0, NP, 2*NP};

  // 1) weight casts (Wq, Wa)
  {
    C2Args a;
    a.in[0]=(const float4*)Wq; a.out[0]=(uint2*)Wqb;
    a.in[1]=(const float4*)Wa; a.out[1]=(uint2*)Wab;
    k_cast2<<<dim3(32,2),256,0,stream>>>(a);
  }
  // 2) fuse all 3 relations
  k_fuse<<<384,256,0,stream>>>(Wk, bk, Wv, bv, rel_att, rel_msg, Wfb, bfu);
  // 3) bucket CSR (1 pass, XCD-affine)
  k_zero_i<<<CDIV(NDST_TOT,256),256,0,stream>>>(cnt_all, NDST_TOT);
  {
    BArgs b;
    const int* dsts[3] = {cites_dst, writes_dst, rev_dst};
    const int* srcs[3] = {cites_src, writes_src, rev_src};
    int Es[3] = {EC, EW, ER};
    int ns[3] = {NP, NP, NA};
    for (int r=0;r<3;r++){
      b.dst[r]=dsts[r]; b.src[r]=srcs[r];
      b.cnt[r]=cnt_all+cntB[r];
      b.slots[r]=slots_all+(size_t)cntB[r]*CAP;
      b.E[r]=Es[r]; b.n[r]=ns[r];
    }
    k_bucket<<<dim3(2048,3),256,0,stream>>>(b);
  }
  // 4) mega GEMM v2: seg0 papers{q,K0,V0}, seg1 authors{q,K1,V1}, seg2 papers{K2,V2}
  {
    const int T0 = CDIV(NP,64), T1 = CDIV(NA,64), T2 = CDIV(NP,64);
    MArgs m;
    m.base[0]=0; m.base[1]=T0; m.base[2]=T0+T1;
    m.X[0]=h_paper;  m.N[0]=NP; m.npan[0]=3;
    m.W[0][0]=Wqb;        m.b[0][0]=bq;        m.Y[0][0]=qbP;      m.ystride[0][0]=128;
    m.W[0][1]=Wfb;        m.b[0][1]=bfu;       m.Y[0][1]=KV0;      m.ystride[0][1]=256;
    m.W[0][2]=Wfb+16384;  m.b[0][2]=bfu+DIM;   m.Y[0][2]=KV0+128;  m.ystride[0][2]=256;
    m.X[1]=h_author; m.N[1]=NA; m.npan[1]=3;
    m.W[1][0]=Wqb+16384;        m.b[1][0]=bq+DIM;        m.Y[1][0]=qbA;      m.ystride[1][0]=128;
    m.W[1][1]=Wfb+32768;        m.b[1][1]=bfu+256;       m.Y[1][1]=KV1;      m.ystride[1][1]=256;
    m.W[1][2]=Wfb+32768+16384;  m.b[1][2]=bfu+256+DIM;   m.Y[1][2]=KV1+128;  m.ystride[1][2]=256;
    m.X[2]=h_paper;  m.N[2]=NP; m.npan[2]=2;
    m.W[2][0]=Wfb+2*32768;        m.b[2][0]=bfu+512;       m.Y[2][0]=KV2;      m.ystride[2][0]=256;
    m.W[2][1]=Wfb+2*32768+16384;  m.b[2][1]=bfu+512+DIM;   m.Y[2][1]=KV2+128;  m.ystride[2][1]=256;
    m.W[2][2]=Wfb;                m.b[2][2]=bfu;           m.Y[2][2]=KV2;      m.ystride[2][2]=256;  // unused
    k_mega<<<T0+T1+T2,512,0,stream>>>(m);
  }
  // 5) fused attention + final GEMM + skip (64 rows/block, 8 waves)
  {
    const int PB = CDIV(NP,64);          // 1563
    const int AB = CDIV(NA,64);          // 782
    AFArgs a;
    a.QP = (const unsigned*)qbP;  a.QA = (const unsigned*)qbA;
    a.KV0 = (const unsigned*)KV0; a.KV1 = (const unsigned*)KV1; a.KV2 = (const unsigned*)KV2;
    a.slots = slots_all; a.cnt = cnt_all;
    a.pri = rel_pri;
    a.WaP = Wab; a.WaA = Wab + 16384;
    a.baP = ba;  a.baA = ba + DIM;
    a.hP = h_paper; a.hA = h_author;
    a.outP = t_paper; a.outA = t_author;
    a.skip = skip;
    a.PB = PB;
    k_attnfin<<<PB+AB,512,0,stream>>>(a);
  }
}

// Round 21
// 309.728 us; speedup vs baseline: 1.0948x; 1.0556x over previous
//
#include <hip/hip_runtime.h>
#include <hip/hip_bf16.h>
#include <math.h>

#define NP 100000
#define NA 50000
#define DIM 128
#define NH 4
#define DKK 32
#define EC 600000
#define EW 300000
#define ER 300000
#define CAP 32          // bucket capacity per dst (Poisson(6) tail ~1e-9)
#define SCL 0.17677669529663687f   // 1/sqrt(32)

#define CDIV(a,b) (((a)+(b)-1)/(b))

typedef __attribute__((ext_vector_type(8))) short bf16x8;
typedef __attribute__((ext_vector_type(4))) float f32x4;
typedef __attribute__((ext_vector_type(2))) float f32x2;

__device__ __forceinline__ ushort f2b(float f){
  unsigned u = __float_as_uint(f);
  unsigned r = u + 0x7FFFu + ((u>>16)&1u);   // RNE
  return (ushort)(r>>16);
}
__device__ __forceinline__ float blo(unsigned u){ return __uint_as_float(u<<16); }
__device__ __forceinline__ float bhi(unsigned u){ return __uint_as_float(u & 0xFFFF0000u); }

// ---------------- prologue combo: cast Wq/Wa  ||  fuse rel weights  ||  zero cnt ----------------
struct PreArgs {
  const float4* wqin; uint2* wqout;
  const float4* wain; uint2* waout;
  const float *Wk, *bk, *Wv, *bv, *rel_att, *rel_msg;
  ushort* Wfb_all; float* bfu_all;
  int* cnt; int ncnt;
};
__global__ void k_pre(PreArgs a){
  int b = blockIdx.x;
  int tid = threadIdx.x;
  if (b < 64){
    // cast: 32 blocks Wq, 32 blocks Wa (8192 float4 each)
    const float4* in = (b < 32) ? a.wqin : a.wain;
    uint2* out = (b < 32) ? a.wqout : a.waout;
    int i = (b & 31)*256 + tid;
    float4 v = in[i];
    uint2 o;
    o.x = (unsigned)f2b(v.x) | ((unsigned)f2b(v.y)<<16);
    o.y = (unsigned)f2b(v.z) | ((unsigned)f2b(v.w)<<16);
    out[i] = o;
  } else if (b < 448){
    int fb = b - 64;                      // 0..383
    int rel = fb >> 7;
    int ts = (rel==1) ? 1 : 0;
    ushort* Wfb = a.Wfb_all + rel*32768;
    float*  bfu = a.bfu_all + rel*256;
    int idx = (fb & 127)*256 + tid;       // 0..32767
    int which = idx >> 14;
    int rem = idx & 16383;
    int op = rem >> 7;
    int j  = rem & 127;
    int h = op >> 5, jp = op & 31;
    const float* W  = which ? a.Wv : a.Wk;
    const float* R  = which ? a.rel_msg : a.rel_att;
    const float* Wt = W + (size_t)ts*DIM*DIM;
    const float* Re = R + (((size_t)rel*NH + h)*DKK)*DKK + jp;
    float acc = 0.f;
    #pragma unroll
    for (int i=0;i<DKK;i++) acc += Wt[(h*DKK+i)*DIM + j] * Re[(size_t)i*DKK];
    Wfb[which*16384 + op*DIM + j] = f2b(acc);
    if (idx < 256){
      int w2 = idx >> 7; int op2 = idx & 127; int h2 = op2>>5, jp2 = op2&31;
      const float* bsrc = (w2 ? a.bv : a.bk) + (size_t)ts*DIM;
      const float* R2 = (w2 ? a.rel_msg : a.rel_att) + (((size_t)rel*NH + h2)*DKK)*DKK + jp2;
      float accb = 0.f;
      #pragma unroll
      for (int i=0;i<DKK;i++) accb += bsrc[h2*DKK+i]*R2[(size_t)i*DKK];
      bfu[w2*DIM + op2] = accb;
    }
  } else {
    int i = (b - 448)*256 + tid;
    if (i < a.ncnt) a.cnt[i] = 0;
  }
}

// ---------------- combo: mega GEMM tiles  ||  XCD-affine bucket scatter ----------------
struct CArgs {
  // mega part
  const float* X[3];
  const ushort* W[3][3];
  const float* b[3][3];
  ushort* Y[3][3];
  int ystride[3][3];
  int N[3];
  int npan[3];
  int base[3];
  int MT;                       // total mega blocks
  // bucket part (1024 blocks per rel, 512 thr, 4 edges/thr)
  const int* dst[3];
  const int* src[3];
  int* cnt[3];
  int* slots[3];
  int E[3];
  int n[3];
};
__global__ __launch_bounds__(512) void k_combo(CArgs g){
  int tid = threadIdx.x;
  if ((int)blockIdx.x >= g.MT){
    // ---------- bucket ----------
    int bb = blockIdx.x - g.MT;
    int r = bb >> 10;
    int lb = bb & 1023;
    int E = g.E[r], n = g.n[r];
    const int* dst = g.dst[r];
    const int* srcv = g.src[r];
    int* cnt = g.cnt[r];
    int* slots = g.slots[r];
    int grp = lb & 7;
    int sub = lb >> 3;                 // 0..127
    int chunk = (n + 7) >> 3;
    int lo = grp*chunk;
    int hi = lo + chunk; if (hi > n) hi = n;
    int per = (E + 127) >> 7;
    per = (per + 3) & ~3;
    int e0 = sub*per;
    int e1 = e0 + per; if (e1 > E) e1 = E;
    for (int i = e0 + tid*4; i < e1; i += 512*4){
      if (i + 4 <= e1){
        int4 d = *(const int4*)(dst + i);
        int4 s = *(const int4*)(srcv + i);
        if (d.x>=lo && d.x<hi){ int p=atomicAdd(&cnt[d.x],1); if(p<CAP) slots[(size_t)d.x*CAP+p]=s.x; }
        if (d.y>=lo && d.y<hi){ int p=atomicAdd(&cnt[d.y],1); if(p<CAP) slots[(size_t)d.y*CAP+p]=s.y; }
        if (d.z>=lo && d.z<hi){ int p=atomicAdd(&cnt[d.z],1); if(p<CAP) slots[(size_t)d.z*CAP+p]=s.z; }
        if (d.w>=lo && d.w<hi){ int p=atomicAdd(&cnt[d.w],1); if(p<CAP) slots[(size_t)d.w*CAP+p]=s.w; }
      } else {
        for (int j=i; j<e1; ++j){
          int d = dst[j];
          if (d>=lo && d<hi){ int p=atomicAdd(&cnt[d],1); if(p<CAP) slots[(size_t)d*CAP+p]=srcv[j]; }
        }
      }
    }
    return;
  }
  // ---------- mega ----------
  int b = blockIdx.x;
  int seg = (b >= g.base[2]) ? 2 : ((b >= g.base[1]) ? 1 : 0);
  int local = b - g.base[seg];
  int N = g.N[seg];
  int tile = local*64;
  if (tile >= N) return;
  int wv = tid >> 6, l = tid & 63;
  int lr = l & 15, lk = l >> 4;
  int rowg = wv >> 1, colg = wv & 1;
  int arow = tile + rowg*16 + lr;
  int ar = (arow < N) ? arow : 0;
  const float4* Ar = (const float4*)(g.X[seg] + (size_t)ar*DIM);
  bf16x8 A[4];
  #pragma unroll
  for (int kc=0;kc<4;kc++){
    float4 u = Ar[kc*8 + lk*2];
    float4 v = Ar[kc*8 + lk*2 + 1];
    bf16x8 a;
    a[0]=(short)f2b(u.x); a[1]=(short)f2b(u.y); a[2]=(short)f2b(u.z); a[3]=(short)f2b(u.w);
    a[4]=(short)f2b(v.x); a[5]=(short)f2b(v.y); a[6]=(short)f2b(v.z); a[7]=(short)f2b(v.w);
    A[kc] = a;
  }
  __shared__ __align__(16) ushort Wl[128*136];
  __shared__ __align__(16) ushort Ost[64*136];
  uint4* Wl4 = (uint4*)Wl;
  int npan = g.npan[seg];
  for (int p=0; p<npan; ++p){
    const uint4* Ws = (const uint4*)g.W[seg][p];
    #pragma unroll
    for (int i=0;i<4;i++){
      int idx = i*512 + tid;
      uint4 v = Ws[idx];
      Wl4[(idx>>4)*17 + (idx&15)] = v;
    }
    __syncthreads();
    const float* bias = g.b[seg][p];
    #pragma unroll
    for (int ct=0; ct<4; ct++){
      int col = colg*64 + ct*16 + lr;
      f32x4 acc = {0.f,0.f,0.f,0.f};
      #pragma unroll
      for (int kc=0;kc<4;kc++){
        bf16x8 B = *(const bf16x8*)&Wl[col*136 + kc*32 + lk*8];
        acc = __builtin_amdgcn_mfma_f32_16x16x32_bf16(A[kc], B, acc, 0, 0, 0);
      }
      float bv = bias[col];
      #pragma unroll
      for (int j=0;j<4;j++)
        Ost[(rowg*16 + lk*4 + j)*136 + col] = f2b(acc[j] + bv);
    }
    __syncthreads();
    int orow = tid >> 3;
    int oseg = (tid & 7)*2;
    int grow = tile + orow;
    if (grow < N){
      uint4* dst = (uint4*)(g.Y[seg][p] + (size_t)grow*g.ystride[seg][p]);
      const uint4* s = (const uint4*)Ost;
      dst[oseg]   = s[orow*17 + oseg];
      dst[oseg+1] = s[orow*17 + oseg + 1];
    }
    __syncthreads();
  }
}

// ---------------- one 4-edge step: K and V halves of one 512B KV row per src ----------------
__device__ __forceinline__ void agg_step4(const unsigned* __restrict__ KV,
    const int4* __restrict__ sl4,
    int i, int deg, int nsrc, float qx, float qy, int lane,
    f32x2& av, float& z)
{
  int4 s4 = sl4[i>>2];
  int s0 = ((unsigned)s4.x < (unsigned)nsrc) ? s4.x : 0;
  int s1 = ((unsigned)s4.y < (unsigned)nsrc) ? s4.y : 0;
  int s2 = ((unsigned)s4.z < (unsigned)nsrc) ? s4.z : 0;
  int s3 = ((unsigned)s4.w < (unsigned)nsrc) ? s4.w : 0;
  bool v1 = (i+1 < deg), v2 = (i+2 < deg), v3 = (i+3 < deg);
  const unsigned* r0 = KV + (size_t)s0*128;
  const unsigned* r1 = KV + (size_t)s1*128;
  const unsigned* r2 = KV + (size_t)s2*128;
  const unsigned* r3 = KV + (size_t)s3*128;
  unsigned ku0 = r0[lane];
  unsigned ku1 = r1[lane];
  unsigned ku2 = r2[lane];
  unsigned ku3 = r3[lane];
  unsigned vu0 = r0[64 + lane];
  unsigned vu1 = r1[64 + lane];
  unsigned vu2 = r2[64 + lane];
  unsigned vu3 = r3[64 + lane];
  float p0 = qx*blo(ku0) + qy*bhi(ku0);
  float p1 = qx*blo(ku1) + qy*bhi(ku1);
  float p2 = qx*blo(ku2) + qy*bhi(ku2);
  float p3 = qx*blo(ku3) + qy*bhi(ku3);
  #pragma unroll
  for (int d=1; d<16; d<<=1){
    p0 += __shfl_xor(p0, d);
    p1 += __shfl_xor(p1, d);
    p2 += __shfl_xor(p2, d);
    p3 += __shfl_xor(p3, d);
  }
  float e0 = __expf(p0);
  float e1 = v1 ? __expf(p1) : 0.f;
  float e2 = v2 ? __expf(p2) : 0.f;
  float e3 = v3 ? __expf(p3) : 0.f;
  z += (e0+e1)+(e2+e3);
  f32x2 w0 = {blo(vu0), bhi(vu0)};
  f32x2 w1 = {blo(vu1), bhi(vu1)};
  f32x2 w2 = {blo(vu2), bhi(vu2)};
  f32x2 w3 = {blo(vu3), bhi(vu3)};
  av += (w0*e0 + w1*e1) + (w2*e2 + w3*e3);
}

// ---------------- fused attention + final GEMM + skip (one block = 64 rows, 8 waves) ----------------
struct AFArgs {
  const unsigned *QP, *QA, *KV0, *KV1, *KV2;
  const int *slots, *cnt;
  const float *pri;
  const ushort *WaP, *WaA;
  const float *baP, *baA;
  const float *hP, *hA;
  float *outP, *outA;
  const float *skip;
  int PB;                     // paper block count
};
__global__ __launch_bounds__(512) void k_attnfin(AFArgs a){
  bool isP = (blockIdx.x < (unsigned)a.PB);
  int wbase = isP ? blockIdx.x*64 : (blockIdx.x - a.PB)*64;
  int N = isP ? NP : NA;
  int tid = threadIdx.x;
  int wid = tid >> 6;
  int lane = tid & 63;
  int h = lane >> 4;
  __shared__ float Ls[64][132];
  __shared__ int nextrow;
  if (tid == 0) nextrow = 0;
  __syncthreads();
  // ---- phase 1: attention, dynamic row queue over 64 rows x 8 waves ----
  for (;;){
    int row;
    if (lane == 0) row = atomicAdd(&nextrow, 1);
    row = __shfl(row, 0);
    if (row >= 64) break;
    int w = wbase + row;
    if (w < N){
      f32x2 o;
      if (isP){
        unsigned qu = a.QP[(size_t)w*64 + lane];
        float qx = blo(qu), qy = bhi(qu);
        float s0f = a.pri[h]*SCL, s1f = a.pri[NH+h]*SCL;
        float qx0 = qx*s0f, qy0 = qy*s0f;
        float qx1 = qx*s1f, qy1 = qy*s1f;
        int d0 = a.cnt[w];      if (d0 > CAP) d0 = CAP;
        int d1 = a.cnt[NP + w]; if (d1 > CAP) d1 = CAP;
        const int4* sl0 = (const int4*)(a.slots + (size_t)w*CAP);
        const int4* sl1 = (const int4*)(a.slots + ((size_t)NP+w)*CAP);
        f32x2 x = {0.f,0.f}, y = {0.f,0.f};
        float zx = 0.f, zy = 0.f;
        int nmax = (d0 > d1) ? d0 : d1;
        for (int i = 0; i < nmax; i += 4){
          if (i < d0) agg_step4(a.KV0, sl0, i, d0, NP, qx0, qy0, lane, x, zx);
          if (i < d1) agg_step4(a.KV1, sl1, i, d1, NA, qx1, qy1, lane, y, zy);
        }
        float ix = (zx > 0.f) ? 1.f/zx : 0.f;
        float iy = (zy > 0.f) ? 1.f/zy : 0.f;
        o = x*ix + y*iy;
      } else {
        unsigned qu = a.QA[(size_t)w*64 + lane];
        float qx = blo(qu), qy = bhi(qu);
        float s2f = a.pri[2*NH+h]*SCL;
        float qx2 = qx*s2f, qy2 = qy*s2f;
        int d2 = a.cnt[2*NP + w]; if (d2 > CAP) d2 = CAP;
        const int4* sl2 = (const int4*)(a.slots + ((size_t)2*NP+w)*CAP);
        f32x2 r = {0.f,0.f};
        float zr = 0.f;
        for (int i = 0; i < d2; i += 4)
          agg_step4(a.KV2, sl2, i, d2, NP, qx2, qy2, lane, r, zr);
        float ir = (zr > 0.f) ? 1.f/zr : 0.f;
        o = r*ir;
      }
      *(f32x2*)&Ls[row][2*lane] = o;
    }
  }
  __syncthreads();
  // ---- phase 2: 64x128 GEMM vs Wa + skip blend (8 waves: rowg=wid>>1, colg=wid&1) ----
  const ushort* Wb  = isP ? a.WaP : a.WaA;
  const float* bias = isP ? a.baP : a.baA;
  const float* hin  = isP ? a.hP  : a.hA;
  float* out        = isP ? a.outP : a.outA;
  float scale       = isP ? 0.5f : 1.0f;
  float alpha = 1.f/(1.f + expf(-a.skip[isP ? 0 : 1]));
  float beta  = 1.f - alpha;
  int lr = lane & 15, lk = lane >> 4;
  int rowg = wid >> 1, colg = wid & 1;
  int r0loc = rowg*16;
  int c0 = colg*64;
  bf16x8 A[4];
  #pragma unroll
  for (int kc=0;kc<4;kc++){
    const float* src = &Ls[r0loc + lr][kc*32 + lk*8];
    bf16x8 aa;
    #pragma unroll
    for (int j=0;j<8;j++) aa[j] = (short)f2b(src[j]);
    A[kc] = aa;
  }
  __syncthreads();   // all A-frags read before Ls overwrite
  #pragma unroll
  for (int ct=0; ct<4; ct++){
    int col = c0 + ct*16 + lr;
    const bf16x8* Wrow = (const bf16x8*)(Wb + (size_t)col*DIM);
    f32x4 acc = {0.f,0.f,0.f,0.f};
    #pragma unroll
    for (int kc=0;kc<4;kc++)
      acc = __builtin_amdgcn_mfma_f32_16x16x32_bf16(A[kc], Wrow[kc*4+lk], acc, 0, 0, 0);
    float bv = bias[col];
    #pragma unroll
    for (int j=0;j<4;j++){
      int lrow = r0loc + lk*4 + j;
      Ls[lrow][col] = scale*acc[j] + bv;
    }
  }
  __syncthreads();
  int orow = tid >> 3;                    // 0..63
  int ocb  = (tid & 7)*16;                // float col base
  int row  = wbase + orow;
  if (row < N){
    const float4* H4 = (const float4*)hin;
    float4* O4 = (float4*)out;
    #pragma unroll
    for (int q=0;q<4;q++){
      float4 tv = *(const float4*)&Ls[orow][ocb + q*4];
      float4 hv = H4[(size_t)row*32 + (ocb>>2) + q];
      float4 o;
      o.x = alpha*tv.x + beta*hv.x;
      o.y = alpha*tv.y + beta*hv.y;
      o.z = alpha*tv.z + beta*hv.z;
      o.w = alpha*tv.w + beta*hv.w;
      O4[(size_t)row*32 + (ocb>>2) + q] = o;
    }
  }
}

extern "C" void kernel_launch(void* const* d_in, const int* in_sizes, int n_in,
                              void* d_out, int out_size, void* d_ws, size_t ws_size,
                              hipStream_t stream) {
  const float* h_paper = (const float*)d_in[0];
  const float* h_author= (const float*)d_in[1];
  const float* Wk = (const float*)d_in[2];
  const float* bk = (const float*)d_in[3];
  const float* Wq = (const float*)d_in[4];
  const float* bq = (const float*)d_in[5];
  const float* Wv = (const float*)d_in[6];
  const float* bv = (const float*)d_in[7];
  const float* Wa = (const float*)d_in[8];
  const float* ba = (const float*)d_in[9];
  const float* rel_att = (const float*)d_in[10];
  const float* rel_msg = (const float*)d_in[11];
  const float* rel_pri = (const float*)d_in[12];
  const float* skip    = (const float*)d_in[13];
  const int* cites_src = (const int*)d_in[14];
  const int* cites_dst = (const int*)d_in[15];
  const int* writes_src= (const int*)d_in[16];
  const int* writes_dst= (const int*)d_in[17];
  const int* rev_src   = (const int*)d_in[18];
  const int* rev_dst   = (const int*)d_in[19];

  // ---- workspace layout (16B aligned) ----
  ushort* qbP = (ushort*)d_ws;                         // NP*128
  ushort* qbA = qbP + (size_t)NP*DIM;                  // NA*128
  ushort* KV0 = qbA + (size_t)NA*DIM;                  // NP*256 (K|V interleaved rows)
  ushort* KV1 = KV0 + (size_t)NP*256;                  // NA*256
  ushort* KV2 = KV1 + (size_t)NA*256;                  // NP*256
  ushort* Wqb = KV2 + (size_t)NP*256;                  // 32768
  ushort* Wab = Wqb + 32768;                           // 32768
  ushort* Wfb = Wab + 32768;                           // 3*32768
  float*  bfu = (float*)(Wfb + 3*32768);               // 3*256
  int* ib = (int*)(bfu + 3*256);
  const int NDST_TOT = 2*NP + NA;                      // 250000
  int* cnt_all   = ib;           ib += NDST_TOT;
  int* slots_all = ib;                                  // 250000*CAP ints = 32 MB

  float* t_paper  = (float*)d_out;
  float* t_author = (float*)d_out + (size_t)NP*DIM;

  const int cntB[3] = {0, NP, 2*NP};

  // 1) prologue combo: cast Wq/Wa || fuse rel weights || zero cnt
  {
    PreArgs p;
    p.wqin = (const float4*)Wq; p.wqout = (uint2*)Wqb;
    p.wain = (const float4*)Wa; p.waout = (uint2*)Wab;
    p.Wk = Wk; p.bk = bk; p.Wv = Wv; p.bv = bv;
    p.rel_att = rel_att; p.rel_msg = rel_msg;
    p.Wfb_all = Wfb; p.bfu_all = bfu;
    p.cnt = cnt_all; p.ncnt = NDST_TOT;
    k_pre<<<448 + CDIV(NDST_TOT,256),256,0,stream>>>(p);
  }
  // 2) combo: mega GEMM (q/KV projections) || bucket scatter (independent work overlapped)
  {
    const int T0 = CDIV(NP,64), T1 = CDIV(NA,64), T2 = CDIV(NP,64);
    const int MT = T0+T1+T2;
    CArgs c;
    c.base[0]=0; c.base[1]=T0; c.base[2]=T0+T1; c.MT = MT;
    c.X[0]=h_paper;  c.N[0]=NP; c.npan[0]=3;
    c.W[0][0]=Wqb;        c.b[0][0]=bq;        c.Y[0][0]=qbP;      c.ystride[0][0]=128;
    c.W[0][1]=Wfb;        c.b[0][1]=bfu;       c.Y[0][1]=KV0;      c.ystride[0][1]=256;
    c.W[0][2]=Wfb+16384;  c.b[0][2]=bfu+DIM;   c.Y[0][2]=KV0+128;  c.ystride[0][2]=256;
    c.X[1]=h_author; c.N[1]=NA; c.npan[1]=3;
    c.W[1][0]=Wqb+16384;        c.b[1][0]=bq+DIM;        c.Y[1][0]=qbA;      c.ystride[1][0]=128;
    c.W[1][1]=Wfb+32768;        c.b[1][1]=bfu+256;       c.Y[1][1]=KV1;      c.ystride[1][1]=256;
    c.W[1][2]=Wfb+32768+16384;  c.b[1][2]=bfu+256+DIM;   c.Y[1][2]=KV1+128;  c.ystride[1][2]=256;
    c.X[2]=h_paper;  c.N[2]=NP; c.npan[2]=2;
    c.W[2][0]=Wfb+2*32768;        c.b[2][0]=bfu+512;       c.Y[2][0]=KV2;      c.ystride[2][0]=256;
    c.W[2][1]=Wfb+2*32768+16384;  c.b[2][1]=bfu+512+DIM;   c.Y[2][1]=KV2+128;  c.ystride[2][1]=256;
    c.W[2][2]=Wfb;                c.b[2][2]=bfu;           c.Y[2][2]=KV2;      c.ystride[2][2]=256;  // unused
    const int* dsts[3] = {cites_dst, writes_dst, rev_dst};
    const int* srcs[3] = {cites_src, writes_src, rev_src};
    int Es[3] = {EC, EW, ER};
    int ns[3] = {NP, NP, NA};
    for (int r=0;r<3;r++){
      c.dst[r]=dsts[r]; c.src[r]=srcs[r];
      c.cnt[r]=cnt_all+cntB[r];
      c.slots[r]=slots_all+(size_t)cntB[r]*CAP;
      c.E[r]=Es[r]; c.n[r]=ns[r];
    }
    k_combo<<<MT + 3*1024,512,0,stream>>>(c);
  }
  // 3) fused attention + final GEMM + skip (64 rows/block, 8 waves)
  {
    const int PB = CDIV(NP,64);          // 1563
    const int AB = CDIV(NA,64);          // 782
    AFArgs a;
    a.QP = (const unsigned*)qbP;  a.QA = (const unsigned*)qbA;
    a.KV0 = (const unsigned*)KV0; a.KV1 = (const unsigned*)KV1; a.KV2 = (const unsigned*)KV2;
    a.slots = slots_all; a.cnt = cnt_all;
    a.pri = rel_pri;
    a.WaP = Wab; a.WaA = Wab + 16384;
    a.baP = ba;  a.baA = ba + DIM;
    a.hP = h_paper; a.hA = h_author;
    a.outP = t_paper; a.outA = t_author;
    a.skip = skip;
    a.PB = PB;
    k_attnfin<<<PB+AB,512,0,stream>>>(a);
  }
}